// Round 4
// baseline (184.714 us; speedup 1.0000x reference)
//
#include <hip/hip_runtime.h>

// B=256, T=256, DM=384, DK=DV=64.
// Round 4: occupancy redesign. The 1024-thr/144KiB block was latency-bound
// at 1 block/CU (pipe demand ~14us, wall 59us). Now: 2 blocks per batch
// (grid 512, 512 thr = 8 waves), each block self-contained:
//   - computes K,V GEMM for ALL 256 tokens (duplicated across the pair; MFMA
//     util was 7%, throughput is free) + Q for its own 8 row-tiles,
//     sharing each staged-W LDS chunk between its two row-tile passes.
//   - full K and V^T live in this block's LDS -> zero cross-block deps.
//   - LDS 75776 B (<80KB) => 2 blocks/CU: sK/sVT unpadded + XOR-swizzle
//     (byte ^= (row&7)<<4), wb staging + Pscr aliased into sK region,
//     Qscr aliased into sVT region.
//   - block h owns tiles 2w+((w^h)&1): 68 S-tiles per block (balanced).
//   - XCD swizzle: both halves of a batch land on the same XCD (L2 x-reuse).

typedef __attribute__((ext_vector_type(8))) short short8;
typedef __attribute__((ext_vector_type(4))) float floatx4;

__device__ inline unsigned short f2bf(float f) {
  union { float f; unsigned u; } v; v.f = f;
  unsigned r = v.u + 0x7FFFu + ((v.u >> 16) & 1u);  // RNE
  return (unsigned short)(r >> 16);
}

__device__ inline void glds16(const void* g, void* l) {
  __builtin_amdgcn_global_load_lds(
      (const __attribute__((address_space(1))) void*)g,
      (__attribute__((address_space(3))) void*)l, 16, 0, 0);
}

// ---------------- kernel 0: weight transpose/convert (output-indexed) -------
__global__ void wt_kernel(const float* __restrict__ wq, const float* __restrict__ wk,
                          const float* __restrict__ wv, unsigned short* __restrict__ wt) {
  int idx = blockIdx.x * 256 + threadIdx.x;      // enumerates OUTPUT [mat][n][k]
  if (idx >= 3 * 64 * 384) return;
  int mat = idx / (64 * 384);
  int rem = idx % (64 * 384);
  int n = rem / 384, k = rem % 384;
  const float* w = (mat == 0) ? wq : ((mat == 1) ? wk : wv);
  wt[idx] = f2bf(w[k * 64 + n]);
}

// ---------------- kernel 1: fused QKV + attention (half-batch blocks) -------
// LDS map (ushort indices, 37888 total = 75776 B):
//   [0,16384)      phase1: wb[2][6144] staging; phase>=3: sK [256 rows][64] swz
//   [16384,32768)  epilogue: Qscr 8x[16][72]; then sVT [64 rows][256 tok] swz
//   [32768,37888)  Pscr 8x[16][40]
__global__ __launch_bounds__(512, 4) void fused_kernel(
    const float* __restrict__ x, const unsigned short* __restrict__ wt,
    float* __restrict__ out) {
  __shared__ __align__(16) unsigned short U[37888];

  int tid = threadIdx.x, lane = tid & 63, w = tid >> 6;   // w: 0..7
  int m = lane & 15, q = lane >> 4;

  // XCD-pair swizzle: blocks i and i+8 (same xcd class) form a batch pair.
  int i = blockIdx.x;
  int xcd = i & 7, jj = i >> 3;
  int b = xcd * 32 + (jj >> 1);                 // batch 0..255
  int h = jj & 1;                               // half 0/1
  const float* xb = x + (size_t)b * 256 * 384;

  int ta = 2 * w + ((w ^ h) & 1);               // own row-tile (attention + Q)
  int tb = 4 * w + 1 - ta;                      // partner tile (K,V only)

  // stage one 32-k chunk of Wt (192 cols) into wb[buf]: 12 x 1KB issues
  auto stage = [&](int ks, int buf) {
#pragma unroll
    for (int t = 0; t < 2; ++t) {
      int sub = w + 8 * t;
      if (sub < 12) {
        int c = sub * 16 + (lane >> 2), g = lane & 3;
        glds16(wt + (size_t)c * 384 + ks * 32 + g * 8,
               (void*)&U[buf * 6144 + sub * 512]);
      }
    }
  };

  floatx4 z = {0.f, 0.f, 0.f, 0.f};
  floatx4 aA[12], aB[8];                        // own QKV / partner KV
#pragma unroll
  for (int nt = 0; nt < 12; ++nt) aA[nt] = z;
#pragma unroll
  for (int nt = 0; nt < 8; ++nt) aB[nt] = z;

  const float* rowa = xb + (size_t)(ta * 16 + m) * 384 + q * 8;
  const float* rowb = xb + (size_t)(tb * 16 + m) * 384 + q * 8;

  stage(0, 0);
#pragma unroll
  for (int ks = 0; ks < 12; ++ks) {
    int buf = ks & 1;
    __syncthreads();                            // wb[buf] staged; buf^1 free
    if (ks < 11) stage(ks + 1, buf ^ 1);

    float4 a0 = *(const float4*)(rowa + ks * 32);
    float4 a1 = *(const float4*)(rowa + ks * 32 + 4);
    float4 b0 = *(const float4*)(rowb + ks * 32);
    float4 b1 = *(const float4*)(rowb + ks * 32 + 4);
    short8 afA, afB;
    afA[0] = (short)f2bf(a0.x); afA[1] = (short)f2bf(a0.y);
    afA[2] = (short)f2bf(a0.z); afA[3] = (short)f2bf(a0.w);
    afA[4] = (short)f2bf(a1.x); afA[5] = (short)f2bf(a1.y);
    afA[6] = (short)f2bf(a1.z); afA[7] = (short)f2bf(a1.w);
    afB[0] = (short)f2bf(b0.x); afB[1] = (short)f2bf(b0.y);
    afB[2] = (short)f2bf(b0.z); afB[3] = (short)f2bf(b0.w);
    afB[4] = (short)f2bf(b1.x); afB[5] = (short)f2bf(b1.y);
    afB[6] = (short)f2bf(b1.z); afB[7] = (short)f2bf(b1.w);

#pragma unroll
    for (int nt = 0; nt < 12; ++nt) {
      // granule = (4m+q) mod 8 -> uniform 8 lanes/group: conflict-free
      short8 bf = *(const short8*)&U[buf * 6144 + (nt * 16 + m) * 32 + q * 8];
      aA[nt] = __builtin_amdgcn_mfma_f32_16x16x32_bf16(afA, bf, aA[nt], 0, 0, 0);
      if (nt >= 4)
        aB[nt - 4] = __builtin_amdgcn_mfma_f32_16x16x32_bf16(afB, bf, aB[nt - 4], 0, 0, 0);
    }
  }

  // ---- Q -> per-wave scratch (sVT region, pre-sVT), read own fragments ----
  unsigned short* qs = U + 16384 + w * 1152;    // [16][72]
#pragma unroll
  for (int nt = 0; nt < 4; ++nt)
#pragma unroll
    for (int j = 0; j < 4; ++j)
      qs[(q * 4 + j) * 72 + nt * 16 + m] = f2bf(aA[nt][j]);
  short8 qf0 = *(const short8*)(qs + m * 72 + q * 8);
  short8 qf1 = *(const short8*)(qs + m * 72 + 32 + q * 8);

  __syncthreads();                              // wb dead, all qf read

  // ---- K (both tiles) -> sK swizzled; V (both tiles) -> sVT swizzled ----
  char* Uc = (char*)U;
#pragma unroll
  for (int n4 = 0; n4 < 4; ++n4) {
#pragma unroll
    for (int j = 0; j < 4; ++j) {
      int ra = ta * 16 + q * 4 + j, ca = n4 * 16 + m;
      int bya = (ra * 128 + ca * 2) ^ ((ra & 7) << 4);
      *(unsigned short*)(Uc + bya) = f2bf(aA[4 + n4][j]);
      int rb = tb * 16 + q * 4 + j;
      int byb = (rb * 128 + ca * 2) ^ ((rb & 7) << 4);
      *(unsigned short*)(Uc + byb) = f2bf(aB[n4][j]);
    }
    int vrow = n4 * 16 + m;
    ushort4 pa, pb;
    pa.x = f2bf(aA[8 + n4][0]); pa.y = f2bf(aA[8 + n4][1]);
    pa.z = f2bf(aA[8 + n4][2]); pa.w = f2bf(aA[8 + n4][3]);
    pb.x = f2bf(aB[4 + n4][0]); pb.y = f2bf(aB[4 + n4][1]);
    pb.z = f2bf(aB[4 + n4][2]); pb.w = f2bf(aB[4 + n4][3]);
    int bva = (vrow * 512 + (ta * 16 + q * 4) * 2) ^ ((vrow & 7) << 4);
    int bvb = (vrow * 512 + (tb * 16 + q * 4) * 2) ^ ((vrow & 7) << 4);
    *(ushort4*)(Uc + 32768 + bva) = pa;
    *(ushort4*)(Uc + 32768 + bvb) = pb;
  }

  __syncthreads();                              // sK, sVT visible; no more barriers

  // ---------- S = Q K^T for own tile r ----------
  int r = ta;
  floatx4 sacc[16];
#pragma unroll
  for (int nt = 0; nt < 16; ++nt) {
    if (nt > r) continue;                       // wave-uniform skip
    int by0 = (((nt * 16 + m) * 128) + q * 16) ^ ((m & 7) << 4);
    short8 kb0 = *(const short8*)(Uc + by0);
    short8 kb1 = *(const short8*)(Uc + (by0 ^ 64));
    floatx4 t = __builtin_amdgcn_mfma_f32_16x16x32_bf16(qf0, kb0, z, 0, 0, 0);
    sacc[nt] = __builtin_amdgcn_mfma_f32_16x16x32_bf16(qf1, kb1, t, 0, 0, 0);
  }

  // ---------- fused causal mask + softmax (no max-subtract) ----------
  const float CSC = 0.18033688011112042f;       // log2(e)/sqrt(64)
  float inv_[4];
  int rbase = r * 16 + q * 4;
#pragma unroll
  for (int j = 0; j < 4; ++j) {
    int rg = rbase + j;
    float sum = 0.f;
#pragma unroll
    for (int nt = 0; nt < 16; ++nt) {
      if (nt > r) continue;
      int col = nt * 16 + m;
      float p = (col <= rg) ? exp2f(sacc[nt][j] * CSC) : 0.f;
      sacc[nt][j] = p;
      sum += p;
    }
    sum += __shfl_xor(sum, 1);
    sum += __shfl_xor(sum, 2);
    sum += __shfl_xor(sum, 4);
    sum += __shfl_xor(sum, 8);
    inv_[j] = 1.f / sum;                        // diagonal term -> sum >= 1
  }

  // ---------- O = P V, 32-token chunks through per-wave Pscr ----------
  unsigned short* ps = U + 32768 + w * 640;     // [16][40]
  floatx4 o[4];
#pragma unroll
  for (int vt = 0; vt < 4; ++vt) o[vt] = z;
#pragma unroll
  for (int c2 = 0; c2 < 8; ++c2) {
    if (2 * c2 > r) continue;                   // chunk needed iff 32c2 <= 16r+15
#pragma unroll
    for (int t = 0; t < 2; ++t) {
      int nt = 2 * c2 + t;
#pragma unroll
      for (int j = 0; j < 4; ++j) {
        unsigned short pv = (nt <= r) ? f2bf(sacc[nt][j] * inv_[j]) : (unsigned short)0;
        ps[(q * 4 + j) * 40 + t * 16 + m] = pv;
      }
    }
    short8 pf = *(const short8*)(ps + m * 40 + q * 8);
#pragma unroll
    for (int vt = 0; vt < 4; ++vt) {
      int bv = (((vt * 16 + m) * 512) + c2 * 64 + q * 16) ^ ((m & 7) << 4);
      short8 vb = *(const short8*)(Uc + 32768 + bv);
      o[vt] = __builtin_amdgcn_mfma_f32_16x16x32_bf16(pf, vb, o[vt], 0, 0, 0);
    }
  }

  // ---------- store O ----------
  float* op = out + ((size_t)b * 256 + r * 16) * 64;
#pragma unroll
  for (int vt = 0; vt < 4; ++vt)
#pragma unroll
    for (int j = 0; j < 4; ++j)
      op[(q * 4 + j) * 64 + vt * 16 + m] = o[vt][j];
}

extern "C" void kernel_launch(void* const* d_in, const int* in_sizes, int n_in,
                              void* d_out, int out_size, void* d_ws, size_t ws_size,
                              hipStream_t stream) {
  const float* x  = (const float*)d_in[0];
  const float* wq = (const float*)d_in[1];
  const float* wk = (const float*)d_in[2];
  const float* wv = (const float*)d_in[3];
  float* out = (float*)d_out;

  unsigned short* wt = (unsigned short*)d_ws;   // Wt bf16 [192][384] = 147456 B

  wt_kernel<<<288, 256, 0, stream>>>(wq, wk, wv, wt);
  fused_kernel<<<512, 512, 0, stream>>>(x, wt, out);
}

// Round 5
// 173.794 us; speedup vs baseline: 1.0628x; 1.0628x over previous
//
#include <hip/hip_runtime.h>

// B=256, T=256, DM=384, DK=DV=64.
// Round 5: revert to round-0 champion structure (1 block/batch, 16 waves),
// retile phase 1 to cut its LDS-read demand 2x.
// k0: W -> Wt bf16 [192 cols][384 k]  (coalesced-output transpose)
// k1: FUSED, one block/batch (1024 thr = 16 waves):
//   Phase 1 (QKV GEMM): wave (rg,cg) = (w>>1, w&1) owns 32 rows x 96 cols
//     (was 16 rows x 192 cols). Block ds_read_b128 per k-step: 192 -> 96;
//     A-loads x2 redundant across the 2 col-groups (L1-served, unique bytes
//     unchanged). B (Wt bf16) staged via global_load_lds, 4 double-buffered
//     mega-chunks of 3 k-chunks; barrier-free inside a mega.
//   Phase 2: Q -> block-shared sQ [256][72] in dead wb[0]; K -> sK; V^T -> sVT
//     (packed ushort4).
//   Phase 3: S=QK^T with triangular wave skip; maskless-fused softmax (no
//     max-subtract: logits bounded, fp32 exp safe).
//   Phase 4: P via per-wave scratch in dead wb[1] (C->A layout), PV from sVT.

typedef __attribute__((ext_vector_type(8))) short short8;
typedef __attribute__((ext_vector_type(4))) float floatx4;

__device__ inline unsigned short f2bf(float f) {
  union { float f; unsigned u; } v; v.f = f;
  unsigned r = v.u + 0x7FFFu + ((v.u >> 16) & 1u);  // RNE
  return (unsigned short)(r >> 16);
}

__device__ inline void glds16(const void* g, void* l) {
  __builtin_amdgcn_global_load_lds(
      (const __attribute__((address_space(1))) void*)g,
      (__attribute__((address_space(3))) void*)l, 16, 0, 0);
}

// ---------------- kernel 0: weight transpose/convert (output-indexed) -------
__global__ void wt_kernel(const float* __restrict__ wq, const float* __restrict__ wk,
                          const float* __restrict__ wv, unsigned short* __restrict__ wt) {
  int idx = blockIdx.x * 256 + threadIdx.x;      // enumerates OUTPUT [mat][n][k]
  if (idx >= 3 * 64 * 384) return;
  int mat = idx / (64 * 384);
  int rem = idx % (64 * 384);
  int n = rem / 384, k = rem % 384;
  const float* w = (mat == 0) ? wq : ((mat == 1) ? wk : wv);
  wt[idx] = f2bf(w[k * 64 + n]);
}

// ---------------- kernel 1: fused QKV + attention ----------------
__global__ __launch_bounds__(1024) void fused_kernel(
    const float* __restrict__ x, const unsigned short* __restrict__ wt,
    float* __restrict__ out) {
  // wb[buf][kc][192 cols][32 k] bf16: 36864B/buf. wb[0] reused as sQ [256][72],
  // wb[1] reused as per-wave P scratch [16][72] x 16 waves.
  __shared__ __align__(16) unsigned short wb[2][3 * 192 * 32];  // 73728 B
  __shared__ __align__(16) unsigned short sK[256 * 72];         // 36864 B
  __shared__ __align__(16) unsigned short sVT[64 * 264];        // 33792 B

  int tid = threadIdx.x, lane = tid & 63, w = tid >> 6;
  int m = lane & 15, q = lane >> 4;
  int rg = w >> 1, cg = w & 1;                  // 8 row-groups x 2 col-groups
  int b = blockIdx.x;
  const float* xb = x + (size_t)b * 256 * 384;

  // stage one mega-chunk (3 k-chunks of 32) of Wt into wb[buf]: 36 x 1KB issues
  auto stage = [&](int mega, int buf) {
#pragma unroll
    for (int t = 0; t < 3; ++t) {
      int i = w + 16 * t;
      if (i < 36) {
        int kc = i / 12, sub = i % 12;
        int c = sub * 16 + (lane >> 2), g = lane & 3;
        glds16(wt + (size_t)c * 384 + (mega * 3 + kc) * 32 + g * 8,
               (void*)&wb[buf][kc * 6144 + sub * 512]);
      }
    }
  };

  floatx4 z = {0.f, 0.f, 0.f, 0.f};
  floatx4 acc[2][6];                            // [row-frag j][col-frag t]
#pragma unroll
  for (int j = 0; j < 2; ++j)
#pragma unroll
    for (int t = 0; t < 6; ++t) acc[j][t] = z;

  stage(0, 0);
#pragma unroll
  for (int mega = 0; mega < 4; ++mega) {
    int buf = mega & 1;
    __syncthreads();                    // wb[buf] staged; prior reads of buf^1 done
    if (mega < 3) stage(mega + 1, buf ^ 1);

#pragma unroll
    for (int kc = 0; kc < 3; ++kc) {
      int ks = mega * 3 + kc;
      const unsigned short* wbk = &wb[buf][kc * 6144];

      short8 af0, af1;
      {
        const float* ap = xb + (size_t)(rg * 32 + m) * 384 + ks * 32 + q * 8;
        float4 f0 = *(const float4*)ap;
        float4 f1 = *(const float4*)(ap + 4);
        af0[0] = (short)f2bf(f0.x); af0[1] = (short)f2bf(f0.y);
        af0[2] = (short)f2bf(f0.z); af0[3] = (short)f2bf(f0.w);
        af0[4] = (short)f2bf(f1.x); af0[5] = (short)f2bf(f1.y);
        af0[6] = (short)f2bf(f1.z); af0[7] = (short)f2bf(f1.w);
      }
      {
        const float* ap = xb + (size_t)(rg * 32 + 16 + m) * 384 + ks * 32 + q * 8;
        float4 f0 = *(const float4*)ap;
        float4 f1 = *(const float4*)(ap + 4);
        af1[0] = (short)f2bf(f0.x); af1[1] = (short)f2bf(f0.y);
        af1[2] = (short)f2bf(f0.z); af1[3] = (short)f2bf(f0.w);
        af1[4] = (short)f2bf(f1.x); af1[5] = (short)f2bf(f1.y);
        af1[6] = (short)f2bf(f1.z); af1[7] = (short)f2bf(f1.w);
      }

#pragma unroll
      for (int t = 0; t < 6; ++t) {
        // granule = (4m+q) mod 8 -> uniform 8 lanes/group: conflict-free
        short8 bf = *(const short8*)&wbk[((cg * 6 + t) * 16 + m) * 32 + q * 8];
        acc[0][t] = __builtin_amdgcn_mfma_f32_16x16x32_bf16(af0, bf, acc[0][t], 0, 0, 0);
        acc[1][t] = __builtin_amdgcn_mfma_f32_16x16x32_bf16(af1, bf, acc[1][t], 0, 0, 0);
      }
    }
  }

  // ---------- epilogue: Q -> sQ (wb[0]), K -> sK, V^T -> sVT ----------
  unsigned short* sQ = &wb[0][0];               // [256][72] bf16
#pragma unroll
  for (int j = 0; j < 2; ++j) {
    int rb2 = rg * 32 + j * 16 + q * 4;         // first of 4 C-layout rows
    if (cg == 0) {
#pragma unroll
      for (int t = 0; t < 4; ++t)               // Q cols 0-63 (nt = t)
#pragma unroll
        for (int jj = 0; jj < 4; ++jj)
          sQ[(rb2 + jj) * 72 + t * 16 + m] = f2bf(acc[j][t][jj]);
#pragma unroll
      for (int t = 4; t < 6; ++t)               // K cols 0-31 (nt = 4,5)
#pragma unroll
        for (int jj = 0; jj < 4; ++jj)
          sK[(rb2 + jj) * 72 + (t - 4) * 16 + m] = f2bf(acc[j][t][jj]);
    } else {
#pragma unroll
      for (int t = 0; t < 2; ++t)               // K cols 32-63 (nt = 6,7)
#pragma unroll
        for (int jj = 0; jj < 4; ++jj)
          sK[(rb2 + jj) * 72 + (t + 2) * 16 + m] = f2bf(acc[j][t][jj]);
#pragma unroll
      for (int t = 2; t < 6; ++t) {             // V cols (nt = 8..11), packed b64
        ushort4 pv;
        pv.x = f2bf(acc[j][t][0]); pv.y = f2bf(acc[j][t][1]);
        pv.z = f2bf(acc[j][t][2]); pv.w = f2bf(acc[j][t][3]);
        *(ushort4*)&sVT[((t - 2) * 16 + m) * 264 + rb2] = pv;
      }
    }
  }

  __syncthreads();                              // sQ, sK, sVT visible to all waves

  // Q fragments for this wave's row-tile (rows [16w, 16w+16))
  short8 qf0 = *(const short8*)(sQ + (w * 16 + m) * 72 + q * 8);
  short8 qf1 = *(const short8*)(sQ + (w * 16 + m) * 72 + 32 + q * 8);

  // ---------- S = Q K^T (triangular: wave w needs col tiles nt <= w) ----------
  floatx4 sacc[16];
#pragma unroll
  for (int nt = 0; nt < 16; ++nt) {
    if (nt > w) continue;                       // wave-uniform skip
    short8 kb0 = *(const short8*)(sK + (nt * 16 + m) * 72 + q * 8);
    short8 kb1 = *(const short8*)(sK + (nt * 16 + m) * 72 + 32 + q * 8);
    floatx4 t = __builtin_amdgcn_mfma_f32_16x16x32_bf16(qf0, kb0, z, 0, 0, 0);
    sacc[nt] = __builtin_amdgcn_mfma_f32_16x16x32_bf16(qf1, kb1, t, 0, 0, 0);
  }

  // ---------- fused causal mask + softmax (no max-subtract) ----------
  const float CSC = 0.18033688011112042f;       // log2(e)/sqrt(64)
  float inv_[4];
  int rbase = w * 16 + q * 4;
#pragma unroll
  for (int j = 0; j < 4; ++j) {
    int rg2 = rbase + j;
    float sum = 0.f;
#pragma unroll
    for (int nt = 0; nt < 16; ++nt) {
      if (nt > w) continue;
      int col = nt * 16 + m;
      float p = (col <= rg2) ? exp2f(sacc[nt][j] * CSC) : 0.f;
      sacc[nt][j] = p;
      sum += p;
    }
    sum += __shfl_xor(sum, 1);
    sum += __shfl_xor(sum, 2);
    sum += __shfl_xor(sum, 4);
    sum += __shfl_xor(sum, 8);
    inv_[j] = 1.f / sum;                        // diagonal term -> sum >= 1
  }

  // ---------- O = P V, chunked by 64 k-cols through per-wave scratch ----------
  unsigned short* scr = &wb[1][0] + w * 1152;   // [16][72] bf16 per wave (dead wb[1])
  floatx4 o[4];
#pragma unroll
  for (int vt = 0; vt < 4; ++vt) o[vt] = z;
#pragma unroll
  for (int c = 0; c < 4; ++c) {
    if (4 * c > w) continue;                    // chunk needed iff 64c <= 16w+15
#pragma unroll
    for (int t = 0; t < 4; ++t) {
      int nt = 4 * c + t;
#pragma unroll
      for (int j = 0; j < 4; ++j) {
        unsigned short pv = (nt <= w) ? f2bf(sacc[nt][j] * inv_[j]) : (unsigned short)0;
        scr[(q * 4 + j) * 72 + t * 16 + m] = pv;
      }
    }
    short8 pf0 = *(const short8*)(scr + m * 72 + q * 8);
    short8 pf1 = *(const short8*)(scr + m * 72 + 32 + q * 8);
#pragma unroll
    for (int vt = 0; vt < 4; ++vt) {
      short8 vb0 = *(const short8*)(sVT + (vt * 16 + m) * 264 + c * 64 + q * 8);
      short8 vb1 = *(const short8*)(sVT + (vt * 16 + m) * 264 + c * 64 + 32 + q * 8);
      o[vt] = __builtin_amdgcn_mfma_f32_16x16x32_bf16(pf0, vb0, o[vt], 0, 0, 0);
      o[vt] = __builtin_amdgcn_mfma_f32_16x16x32_bf16(pf1, vb1, o[vt], 0, 0, 0);
    }
  }

  // ---------- store O ----------
  float* op = out + ((size_t)b * 256 + w * 16) * 64;
#pragma unroll
  for (int vt = 0; vt < 4; ++vt)
#pragma unroll
    for (int j = 0; j < 4; ++j)
      op[(q * 4 + j) * 64 + vt * 16 + m] = o[vt][j];
}

extern "C" void kernel_launch(void* const* d_in, const int* in_sizes, int n_in,
                              void* d_out, int out_size, void* d_ws, size_t ws_size,
                              hipStream_t stream) {
  const float* x  = (const float*)d_in[0];
  const float* wq = (const float*)d_in[1];
  const float* wk = (const float*)d_in[2];
  const float* wv = (const float*)d_in[3];
  float* out = (float*)d_out;

  unsigned short* wt = (unsigned short*)d_ws;   // Wt bf16 [192][384] = 147456 B

  wt_kernel<<<288, 256, 0, stream>>>(wq, wk, wv, wt);
  fused_kernel<<<256, 1024, 0, stream>>>(x, wt, out);
}